// Round 19
// baseline (132.755 us; speedup 1.0000x reference)
//
#include <hip/hip_runtime.h>
#include <hip/hip_bf16.h>
#include <stdint.h>

#define D_MODEL 1024
#define NH 16
#define DH 64
#define SEQ 2048
#define MROWS 4096   // B*S
#define LOG2E 1.44269504088896340736f

typedef unsigned short ushort_t;
typedef __attribute__((ext_vector_type(4))) float f32x4;
typedef __attribute__((ext_vector_type(16))) float f32x16;
typedef __attribute__((ext_vector_type(4))) unsigned short us4;
typedef __attribute__((ext_vector_type(8))) unsigned short us8;
typedef __attribute__((ext_vector_type(4))) unsigned int u32x4;
typedef __attribute__((ext_vector_type(8))) __bf16 bf16x8;

__device__ __forceinline__ f32x4 mfma16(us8 a, us8 b, f32x4 c) {
    return __builtin_amdgcn_mfma_f32_16x16x32_bf16(
        __builtin_bit_cast(bf16x8, a), __builtin_bit_cast(bf16x8, b), c, 0, 0, 0);
}
__device__ __forceinline__ f32x16 mfma32(us8 a, us8 b, f32x16 c) {
    return __builtin_amdgcn_mfma_f32_32x32x16_bf16(
        __builtin_bit_cast(bf16x8, a), __builtin_bit_cast(bf16x8, b), c, 0, 0, 0);
}

// packed f32x2 -> bf16x2, RNE (verified == manual RNE in rounds 7-18)
__device__ __forceinline__ unsigned int cvtpk(float lo, float hi) {
    unsigned int r;
    asm("v_cvt_pk_bf16_f32 %0, %1, %2" : "=v"(r) : "v"(lo), "v"(hi));
    return r;
}
// single f32 -> bf16 (1 VALU op)
__device__ __forceinline__ ushort_t f2bf1(float f) {
    return (ushort_t)(cvtpk(f, f) & 0xffffu);
}

__device__ __forceinline__ float exp2_fast(float x) {
#if __has_builtin(__builtin_amdgcn_exp2f)
    return __builtin_amdgcn_exp2f(x);
#else
    float r; asm("v_exp_f32 %0, %1" : "=v"(r) : "v"(x)); return r;
#endif
}

// async global->LDS, 16B per lane; LDS base wave-uniform, lane i at base+i*16
__device__ __forceinline__ void gload16(const void* g, void* l) {
    __builtin_amdgcn_global_load_lds(
        (const __attribute__((address_space(1))) void*)g,
        (__attribute__((address_space(3))) void*)l, 16, 0, 0);
}

// ---------------------------------------------------------------------------
// fused fp32 -> bf16 convert (weights only); z picks pair; n4 = float4 count
// ---------------------------------------------------------------------------
__global__ __launch_bounds__(256) void conv_multi(
    const float* __restrict__ s0, ushort_t* __restrict__ d0,
    const float* __restrict__ s1, ushort_t* __restrict__ d1,
    const float* __restrict__ s2, ushort_t* __restrict__ d2,
    const float* __restrict__ s3, ushort_t* __restrict__ d3, int n4)
{
    int z = blockIdx.z;
    const float* s = z == 0 ? s0 : z == 1 ? s1 : z == 2 ? s2 : s3;
    ushort_t* d    = z == 0 ? d0 : z == 1 ? d1 : z == 2 ? d2 : d3;
    int i = blockIdx.x * 256 + threadIdx.x;
    int stride = gridDim.x * 256;
    for (; i < n4; i += stride) {
        float4 v = ((const float4*)s)[i];
        uint2 pr;
        pr.x = cvtpk(v.x, v.y);
        pr.y = cvtpk(v.z, v.w);
        ((uint2*)d)[i] = pr;
    }
}

// ---------------------------------------------------------------------------
// mask tile flags at 64x64 granularity
// ---------------------------------------------------------------------------
__global__ __launch_bounds__(256) void mask_flags(const float* __restrict__ mask,
                                                  int* __restrict__ flags)
{
    int qt = blockIdx.x, kt = blockIdx.y;
    int t = threadIdx.x;
    bool nz = false;
#pragma unroll
    for (int i = 0; i < 4; i++) {
        int idx = t + i * 256;               // 1024 float4: 64 rows x 16
        int row = idx >> 4, c4 = (idx & 15) * 4;
        float4 v = *(const float4*)(mask + (size_t)(qt * 64 + row) * SEQ + kt * 64 + c4);
        nz |= (v.x != 0.f) | (v.y != 0.f) | (v.z != 0.f) | (v.w != 0.f);
    }
    if (__any((int)nz) && (t & 63) == 0) atomicOr(&flags[qt * 32 + kt], 1);
}

// ---------------------------------------------------------------------------
// GEMM staging, XOR-SWIZZLED LDS (r18-verified: conflicts 14.16M -> 0):
//   gload16 paths: pre-swizzled global source column, linear LDS dest.
//   fp32 A path: T14 issue-early/write-late split -- loads for tile k+1
//   issue BEFORE tile k's fragment reads (full MFMA window to land), the
//   cvtpk + swizzled ds_write happen AFTER MFMA, just before the barrier.
// ---------------------------------------------------------------------------
__device__ __forceinline__ void stageB_bf16(const ushort_t* __restrict__ B,
                                            int n0, int t, int w, int k0,
                                            ushort_t* sB)
{
#pragma unroll
    for (int r = 0; r < 2; r++) {
        int chunk = r * 256 + t;
        int row = chunk >> 3, cc = (chunk & 7) ^ (row & 7);
        gload16(B + (size_t)(n0 + row) * D_MODEL + k0 + cc * 8,
                &sB[(r * 256 + w * 64) * 8]);
    }
}

__device__ __forceinline__ void stageA_bf16(const ushort_t* __restrict__ A,
                                            int m0, int t, int w, int k0,
                                            ushort_t* sA)
{
#pragma unroll
    for (int r = 0; r < 4; r++) {
        int chunk = r * 256 + t;                   // 1024 chunks of 8 bf16
        int row = chunk >> 3, cc = (chunk & 7) ^ (row & 7);
        gload16(A + (size_t)(m0 + row) * D_MODEL + k0 + cc * 8,
                &sA[(r * 256 + w * 64) * 8]);
    }
}

// issue fp32 loads for one A tile into registers (no waiting)
__device__ __forceinline__ void loadA_f32(const float* __restrict__ A,
                                          int m0, int t, int k0,
                                          float4 la[4][2])
{
#pragma unroll
    for (int r = 0; r < 4; r++) {
        int chunk = r * 256 + t;
        int row = chunk >> 3, c = chunk & 7;
        const float* src = A + (size_t)(m0 + row) * D_MODEL + k0 + c * 8;
        la[r][0] = *(const float4*)src;
        la[r][1] = *(const float4*)(src + 4);
    }
}

// convert + write one A tile to swizzled LDS (waits on the loads here)
__device__ __forceinline__ void writeA_f32(const float4 la[4][2], int t,
                                           ushort_t* sA)
{
#pragma unroll
    for (int r = 0; r < 4; r++) {
        int chunk = r * 256 + t;
        int row = chunk >> 3, c = chunk & 7;
        u32x4 pw;
        pw[0] = cvtpk(la[r][0].x, la[r][0].y);
        pw[1] = cvtpk(la[r][0].z, la[r][0].w);
        pw[2] = cvtpk(la[r][1].x, la[r][1].y);
        pw[3] = cvtpk(la[r][1].z, la[r][1].w);
        int by = (row * 128 + c * 16) ^ ((row & 7) << 4);   // swizzled dest
        *(u32x4*)((char*)sA + by) = pw;
    }
}

// ---------------------------------------------------------------------------
// fused QKV projection: z=0 qx@Wq^T -> Qb (scaled, [B,H,S,Dh]); z=1 kx@Wk^T
// -> Kb; z=2 vx@Wv^T -> VT ([B,H,Dh,S]). A from fp32 with T14 split staging.
// BM=128 BN=64 BK=64, 2-phase dbuf, 1536 blocks = 3/CU. Swizzled LDS.
// ---------------------------------------------------------------------------
__global__ __launch_bounds__(256) void gemm_qkv(const float* __restrict__ qx,
                                                const float* __restrict__ kx,
                                                const float* __restrict__ vx,
                                                const ushort_t* __restrict__ Wq,
                                                const ushort_t* __restrict__ Wk,
                                                const ushort_t* __restrict__ Wv,
                                                ushort_t* __restrict__ Qo,
                                                ushort_t* __restrict__ Ko,
                                                ushort_t* __restrict__ VT)
{
    __shared__ ushort_t sA[2][128 * 64];
    __shared__ ushort_t sB[2][64 * 64];
    const int z = blockIdx.z;
    const float* A = z == 0 ? qx : z == 1 ? kx : vx;
    const ushort_t* W = z == 0 ? Wq : z == 1 ? Wk : Wv;
    const int t = threadIdx.x, lane = t & 63, w = t >> 6;
    const int lr = lane & 15, lg = lane >> 4;
    const int wm = (w >> 1) * 64, wn = (w & 1) * 32;
    const int m0 = blockIdx.x * 128, n0 = blockIdx.y * 64;

    f32x4 acc[4][2];
    f32x4 zero = {0.f, 0.f, 0.f, 0.f};
#pragma unroll
    for (int i = 0; i < 4; i++)
#pragma unroll
        for (int j = 0; j < 2; j++) acc[i][j] = zero;

    {
        float4 la0[4][2];
        loadA_f32(A, m0, t, 0, la0);
        stageB_bf16(W, n0, t, w, 0, &sB[0][0]);
        writeA_f32(la0, t, &sA[0][0]);
    }
    __syncthreads();

    for (int it = 0; it < D_MODEL / 64; ++it) {
        const int cur = it & 1;
        const char* cA = (const char*)&sA[cur][0];
        const char* cB = (const char*)&sB[cur][0];
        const bool more = (it + 1 < D_MODEL / 64);

        // ---- T14 issue-early: fp32 loads for next tile, BEFORE frag reads ----
        float4 la[4][2];
        if (more) loadA_f32(A, m0, t, (it + 1) * 64, la);

        // ---- ds_read all fragments of current buffer (swizzled) ----
        us8 af[4][2], bfr[2][2];
#pragma unroll
        for (int i = 0; i < 4; i++)
#pragma unroll
            for (int ks = 0; ks < 2; ks++) {
                int row = wm + i * 16 + lr;
                af[i][ks] = *(const us8*)(cA + ((row * 128 + (ks * 32 + 8 * lg) * 2)
                                                ^ ((row & 7) << 4)));
            }
#pragma unroll
        for (int j = 0; j < 2; j++)
#pragma unroll
            for (int ks = 0; ks < 2; ks++) {
                int row = wn + j * 16 + lr;
                bfr[j][ks] = *(const us8*)(cB + ((row * 128 + (ks * 32 + 8 * lg) * 2)
                                                 ^ ((row & 7) << 4)));
            }

        // ---- B stage (async gload16, after reads per r9 alias lesson) ----
        if (more) stageB_bf16(W, n0, t, w, (it + 1) * 64, &sB[cur ^ 1][0]);

        // ---- MFMA (loads fly underneath) ----
#pragma unroll
        for (int i = 0; i < 4; i++)
#pragma unroll
            for (int j = 0; j < 2; j++)
#pragma unroll
                for (int ks = 0; ks < 2; ks++)
                    acc[i][j] = mfma16(af[i][ks], bfr[j][ks], acc[i][j]);

        // ---- T14 write-late: convert + ds_write next A tile ----
        if (more) writeA_f32(la, t, &sA[cur ^ 1][0]);

        __syncthreads();
    }

    // ---- epilogues ----
    if (z < 2) {
        ushort_t* C = z ? Ko : Qo;
        const float scale = z ? 1.0f : 0.125f * LOG2E;   // scores in log2 units
#pragma unroll
        for (int i = 0; i < 4; i++)
#pragma unroll
            for (int j = 0; j < 2; j++)
#pragma unroll
                for (int r = 0; r < 4; r++) {
                    int m = m0 + wm + i * 16 + 4 * lg + r;   // token (b*S+s)
                    int n = n0 + wn + j * 16 + lr;           // feature
                    int b = m >> 11, s = m & 2047;
                    int h = n >> 6, dh = n & 63;
                    C[(((size_t)(b * NH + h)) * SEQ + s) * DH + dh] = f2bf1(acc[i][j][r] * scale);
                }
    } else {
#pragma unroll
        for (int i = 0; i < 4; i++)
#pragma unroll
            for (int j = 0; j < 2; j++) {
                int m = m0 + wm + i * 16 + 4 * lg;           // s base; r adds 0..3
                int n = n0 + wn + j * 16 + lr;
                int b = m >> 11, s = m & 2047;
                int h = n >> 6, dh = n & 63;
                uint2 pr;
                pr.x = cvtpk(acc[i][j][0], acc[i][j][1]);
                pr.y = cvtpk(acc[i][j][2], acc[i][j][3]);
                *(uint2*)&VT[(((size_t)(b * NH + h)) * DH + dh) * SEQ + s] = pr;
            }
    }
}

// output projection: A bf16 [4096][1024] @ W0^T -> fp32 [4096][1024]
// (2-phase dbuf, swizzled LDS, gload16 both operands)
__global__ __launch_bounds__(256) void gemm_o(const ushort_t* __restrict__ A,
                                              const ushort_t* __restrict__ W,
                                              float* __restrict__ C)
{
    __shared__ ushort_t sA[2][128 * 64];
    __shared__ ushort_t sB[2][64 * 64];
    const int t = threadIdx.x, lane = t & 63, w = t >> 6;
    const int lr = lane & 15, lg = lane >> 4;
    const int wm = (w >> 1) * 64, wn = (w & 1) * 32;
    const int m0 = blockIdx.x * 128, n0 = blockIdx.y * 64;

    f32x4 acc[4][2];
    f32x4 zero = {0.f, 0.f, 0.f, 0.f};
#pragma unroll
    for (int i = 0; i < 4; i++)
#pragma unroll
        for (int j = 0; j < 2; j++) acc[i][j] = zero;

    stageA_bf16(A, m0, t, w, 0, &sA[0][0]);
    stageB_bf16(W, n0, t, w, 0, &sB[0][0]);
    __syncthreads();

    for (int it = 0; it < D_MODEL / 64; ++it) {
        const int cur = it & 1;
        const char* cA = (const char*)&sA[cur][0];
        const char* cB = (const char*)&sB[cur][0];

        us8 af[4][2], bfr[2][2];
#pragma unroll
        for (int i = 0; i < 4; i++)
#pragma unroll
            for (int ks = 0; ks < 2; ks++) {
                int row = wm + i * 16 + lr;
                af[i][ks] = *(const us8*)(cA + ((row * 128 + (ks * 32 + 8 * lg) * 2)
                                                ^ ((row & 7) << 4)));
            }
#pragma unroll
        for (int j = 0; j < 2; j++)
#pragma unroll
            for (int ks = 0; ks < 2; ks++) {
                int row = wn + j * 16 + lr;
                bfr[j][ks] = *(const us8*)(cB + ((row * 128 + (ks * 32 + 8 * lg) * 2)
                                                 ^ ((row & 7) << 4)));
            }

        if (it + 1 < D_MODEL / 64) {
            stageA_bf16(A, m0, t, w, (it + 1) * 64, &sA[cur ^ 1][0]);
            stageB_bf16(W, n0, t, w, (it + 1) * 64, &sB[cur ^ 1][0]);
        }

#pragma unroll
        for (int i = 0; i < 4; i++)
#pragma unroll
            for (int j = 0; j < 2; j++)
#pragma unroll
                for (int ks = 0; ks < 2; ks++)
                    acc[i][j] = mfma16(af[i][ks], bfr[j][ks], acc[i][j]);

        __syncthreads();
    }

#pragma unroll
    for (int i = 0; i < 4; i++)
#pragma unroll
        for (int j = 0; j < 2; j++)
#pragma unroll
            for (int r = 0; r < 4; r++) {
                int m = m0 + wm + i * 16 + 4 * lg + r;
                int n = n0 + wn + j * 16 + lr;
                C[(size_t)m * D_MODEL + n] = acc[i][j][r];
            }
}

// ---------------------------------------------------------------------------
// Flash attention (round-15 exact): swapped-operand 32x32x16, KVBLK=64 dbuf,
// 32 KB LDS, launch_bounds(256,2), max-free softmax, permlane P-assembly,
// l on VALU, XCD swizzle, hoisted stage ptrs.
// C/D layout (HW-verified): col=lane&31, row=(r&3)+8*(r>>2)+4*(lane>>5).
// ---------------------------------------------------------------------------
__global__ __launch_bounds__(256, 2) void attn_fwd(const ushort_t* __restrict__ Q,
                                                   const ushort_t* __restrict__ K,
                                                   const ushort_t* __restrict__ VT,
                                                   const float* __restrict__ mask,
                                                   const int* __restrict__ flags,
                                                   ushort_t* __restrict__ O)
{
    __shared__ ushort_t sK[2][64 * 64];     // 64 kv rows x 64 dh  (8 KB each)
    __shared__ ushort_t sVT[2][64 * 64];    // 64 dh rows x 64 kv

    const int t = threadIdx.x, lane = t & 63, w = t >> 6;
    const int l31 = lane & 31, lh = lane >> 5;
    const int id = blockIdx.x;
    const int bh = (id & 7) * 4 + ((id >> 3) >> 4);   // XCD-contiguous heads
    const int qt = (id >> 3) & 15;
    const int b = bh >> 4, h = bh & 15;
    const int q = qt * 128 + w * 32 + l31;   // lane's q row

    // mask-tile flags for this 128-row q block (2 flag rows ORed); bit = 64-col tile
    unsigned long long blt = __ballot(flags[(qt * 2 + lh) * 32 + l31] != 0);
    const unsigned int fl = (unsigned int)(blt | (blt >> 32));

    // Q fragments: B-operand rows = q, k(d)-slots 16*ks + 8*lh + e
    us8 qfr[4];
#pragma unroll
    for (int ks = 0; ks < 4; ks++)
        qfr[ks] = *(const us8*)(Q + ((size_t)bh * SEQ + q) * DH + ks * 16 + 8 * lh);

    f32x16 acc_o[2];
#pragma unroll
    for (int d = 0; d < 2; d++)
#pragma unroll
        for (int r = 0; r < 16; r++) acc_o[d][r] = 0.f;
    float acc_l = 0.f;

    const ushort_t* Kb = K + (size_t)bh * SEQ * DH;
    const ushort_t* Vb = VT + (size_t)bh * DH * SEQ;

    // hoisted per-thread staging source pointers (advance by const per tile)
    const ushort_t* kp[2];
    const ushort_t* vp[2];
#pragma unroll
    for (int r = 0; r < 2; r++) {
        int j = r * 256 + t;                 // 512 chunks of 16B per tensor
        int row = j >> 3, cc = (j & 7) ^ (row & 7);
        kp[r] = Kb + (size_t)row * DH + cc * 8;
        vp[r] = Vb + (size_t)row * SEQ + cc * 8;
    }

#define STAGE(kvt_, buf_)                                                     \
    {                                                                         \
        _Pragma("unroll")                                                     \
        for (int r = 0; r < 2; r++)                                           \
            gload16(kp[r] + (size_t)(kvt_) * (64 * DH),                       \
                    &sK[buf_][(r * 256 + w * 64) * 8]);                       \
        _Pragma("unroll")                                                     \
        for (int r = 0; r < 2; r++)                                           \
            gload16(vp[r] + (size_t)(kvt_) * 64,                              \
                    &sVT[buf_][(r * 256 + w * 64) * 8]);                      \
    }

    STAGE(0, 0);
    __syncthreads();

    for (int kvt = 0; kvt < SEQ / 64; ++kvt) {
        const int cur = kvt & 1;
        const char* cK = (const char*)sK[cur];
        const char* cV = (const char*)sVT[cur];

        // ---- S = K Q^T: sacc[kb][r] = S[kcol=kb*32+crow(r,lh)][q] ----
        f32x16 sacc[2];
#pragma unroll
        for (int kb = 0; kb < 2; kb++)
#pragma unroll
            for (int r = 0; r < 16; r++) sacc[kb][r] = 0.f;
        __builtin_amdgcn_s_setprio(1);
#pragma unroll
        for (int ks = 0; ks < 4; ks++)
#pragma unroll
            for (int kb = 0; kb < 2; kb++) {
                int row = kb * 32 + l31;
                int by = (row * 128 + (ks * 16 + 8 * lh) * 2) ^ ((row & 7) << 4);
                us8 kf = *(const us8*)(cK + by);
                sacc[kb] = mfma32(kf, qfr[ks], sacc[kb]);
            }
        __builtin_amdgcn_s_setprio(0);

        // ---- V-frag reads (last ds_reads of this tile) ----
        us8 vf[4][2];
#pragma unroll
        for (int ks = 0; ks < 4; ks++)
#pragma unroll
            for (int dblk = 0; dblk < 2; dblk++) {
                int row = dblk * 32 + l31;
                int by = (row * 128 + (ks * 16 + 8 * lh) * 2) ^ ((row & 7) << 4);
                vf[ks][dblk] = *(const us8*)(cV + by);
            }

        // ---- stage next tile; loads hide under softmax + PV ----
        if (kvt + 1 < SEQ / 64) STAGE(kvt + 1, cur ^ 1);

        // ---- additive mask (log2; skipped when 64-col tile all-zero) ----
        if ((fl >> kvt) & 1u) {
#pragma unroll
            for (int kb = 0; kb < 2; kb++)
#pragma unroll
                for (int r = 0; r < 16; r++) {
                    int kcol = kb * 32 + (r & 3) + 8 * (r >> 2) + 4 * lh;
                    sacc[kb][r] += mask[(size_t)q * SEQ + kvt * 64 + kcol] * LOG2E;
                }
        }

        // ---- P = exp2(S) in place (max-free); l partial sum ----
        float rs = 0.f;
#pragma unroll
        for (int kb = 0; kb < 2; kb++)
#pragma unroll
            for (int r = 0; r < 16; r++) {
                float p = exp2_fast(sacc[kb][r]);
                sacc[kb][r] = p;
                rs += p;
            }
        rs += __shfl_xor(rs, 32);
        acc_l += rs;

        // ---- PV: P B-frags via cvt_pk + permlane32_swap (verified r12) ----
        __builtin_amdgcn_s_setprio(1);
#pragma unroll
        for (int ks = 0; ks < 4; ks++) {
            const int kb = ks >> 1, u = ks & 1;
            unsigned int W0 = cvtpk(sacc[kb][8 * u + 0], sacc[kb][8 * u + 1]);
            unsigned int W1 = cvtpk(sacc[kb][8 * u + 2], sacc[kb][8 * u + 3]);
            unsigned int W2 = cvtpk(sacc[kb][8 * u + 4], sacc[kb][8 * u + 5]);
            unsigned int W3 = cvtpk(sacc[kb][8 * u + 6], sacc[kb][8 * u + 7]);
            asm("v_permlane32_swap_b32 %0, %1" : "+v"(W0), "+v"(W2));
            asm("v_permlane32_swap_b32 %0, %1" : "+v"(W1), "+v"(W3));
            u32x4 pw;
            pw[0] = W0; pw[1] = W1; pw[2] = W2; pw[3] = W3;
            us8 pf = __builtin_bit_cast(us8, pw);
#pragma unroll
            for (int dblk = 0; dblk < 2; dblk++)
                acc_o[dblk] = mfma32(vf[ks][dblk], pf, acc_o[dblk]);
        }
        __builtin_amdgcn_s_setprio(0);

        __syncthreads();   // drains stage(kvt+1); protects buf reuse
    }

    // ---- normalize + write [B*S][D] bf16 (d = dblk*32 + 8g + 4lh + 0..3) ----
    float inv = 1.f / acc_l;
    ushort_t* Orow = O + ((size_t)(b * SEQ) + q) * D_MODEL + h * DH;
#pragma unroll
    for (int dblk = 0; dblk < 2; dblk++)
#pragma unroll
        for (int g = 0; g < 4; g++) {
            unsigned int lo = cvtpk(acc_o[dblk][4 * g + 0] * inv,
                                    acc_o[dblk][4 * g + 1] * inv);
            unsigned int hi = cvtpk(acc_o[dblk][4 * g + 2] * inv,
                                    acc_o[dblk][4 * g + 3] * inv);
            uint2 pr; pr.x = lo; pr.y = hi;
            *(uint2*)(Orow + dblk * 32 + 8 * g + 4 * lh) = pr;
        }
#undef STAGE
}

// ---------------------------------------------------------------------------
extern "C" void kernel_launch(void* const* d_in, const int* in_sizes, int n_in,
                              void* d_out, int out_size, void* d_ws, size_t ws_size,
                              hipStream_t stream)
{
    const float* qx   = (const float*)d_in[0];
    const float* kx   = (const float*)d_in[1];
    const float* vx   = (const float*)d_in[2];
    const float* mask = (const float*)d_in[3];
    const float* wq   = (const float*)d_in[4];
    const float* wk   = (const float*)d_in[5];
    const float* wv   = (const float*)d_in[6];
    const float* w0   = (const float*)d_in[7];
    float* out = (float*)d_out;

    char* ws = (char*)d_ws;
    const size_t MB = 1024 * 1024;
    ushort_t* AO = (ushort_t*)(ws + 8 * MB);        // attn out bf16, 8 MB
    ushort_t* Wq = (ushort_t*)(ws + 16 * MB);       // 2 MB each
    ushort_t* Wk = (ushort_t*)(ws + 18 * MB);
    ushort_t* Wv = (ushort_t*)(ws + 20 * MB);
    ushort_t* W0 = (ushort_t*)(ws + 22 * MB);
    ushort_t* VT = (ushort_t*)(ws + 24 * MB);       // [B,H,Dh,S] bf16, 8 MB
    int* flags   = (int*)(ws + 32 * MB);            // [32][32]
    // Q and K (bf16, [B,H,S,Dh]) live in d_out until attn consumes them
    ushort_t* Qb = (ushort_t*)d_out;
    ushort_t* Kb = (ushort_t*)d_out + 4 * MB;       // +8 MB bytes

    hipMemsetAsync(flags, 0, 32 * 32 * sizeof(int), stream);
    mask_flags<<<dim3(32, 32), 256, 0, stream>>>(mask, flags);

    // weights fp32 -> bf16 (one fused launch)
    conv_multi<<<dim3(256, 1, 4), 256, 0, stream>>>(wq, Wq, wk, Wk, wv, Wv, w0, W0, 262144);

    // fused QKV projections, A converted in-kernel from fp32 (T14 split)
    gemm_qkv<<<dim3(32, 16, 3), 256, 0, stream>>>(qx, kx, vx, Wq, Wk, Wv, Qb, Kb, VT);

    attn_fwd<<<512, 256, 0, stream>>>(Qb, Kb, VT, mask, flags, AO);

    gemm_o<<<dim3(32, 16), 256, 0, stream>>>(AO, W0, out);
}

// Round 20
// 127.242 us; speedup vs baseline: 1.0433x; 1.0433x over previous
//
#include <hip/hip_runtime.h>
#include <hip/hip_bf16.h>
#include <stdint.h>

#define D_MODEL 1024
#define NH 16
#define DH 64
#define SEQ 2048
#define MROWS 4096   // B*S
#define LOG2E 1.44269504088896340736f

typedef unsigned short ushort_t;
typedef __attribute__((ext_vector_type(4))) float f32x4;
typedef __attribute__((ext_vector_type(16))) float f32x16;
typedef __attribute__((ext_vector_type(4))) unsigned short us4;
typedef __attribute__((ext_vector_type(8))) unsigned short us8;
typedef __attribute__((ext_vector_type(4))) unsigned int u32x4;
typedef __attribute__((ext_vector_type(8))) __bf16 bf16x8;

__device__ __forceinline__ f32x4 mfma16(us8 a, us8 b, f32x4 c) {
    return __builtin_amdgcn_mfma_f32_16x16x32_bf16(
        __builtin_bit_cast(bf16x8, a), __builtin_bit_cast(bf16x8, b), c, 0, 0, 0);
}
__device__ __forceinline__ f32x16 mfma32(us8 a, us8 b, f32x16 c) {
    return __builtin_amdgcn_mfma_f32_32x32x16_bf16(
        __builtin_bit_cast(bf16x8, a), __builtin_bit_cast(bf16x8, b), c, 0, 0, 0);
}

// packed f32x2 -> bf16x2, RNE (verified == manual RNE in rounds 7-19)
__device__ __forceinline__ unsigned int cvtpk(float lo, float hi) {
    unsigned int r;
    asm("v_cvt_pk_bf16_f32 %0, %1, %2" : "=v"(r) : "v"(lo), "v"(hi));
    return r;
}
// single f32 -> bf16 (1 VALU op)
__device__ __forceinline__ ushort_t f2bf1(float f) {
    return (ushort_t)(cvtpk(f, f) & 0xffffu);
}

__device__ __forceinline__ float exp2_fast(float x) {
#if __has_builtin(__builtin_amdgcn_exp2f)
    return __builtin_amdgcn_exp2f(x);
#else
    float r; asm("v_exp_f32 %0, %1" : "=v"(r) : "v"(x)); return r;
#endif
}

// async global->LDS, 16B per lane; LDS base wave-uniform, lane i at base+i*16
__device__ __forceinline__ void gload16(const void* g, void* l) {
    __builtin_amdgcn_global_load_lds(
        (const __attribute__((address_space(1))) void*)g,
        (__attribute__((address_space(3))) void*)l, 16, 0, 0);
}

// ---------------------------------------------------------------------------
// fused fp32 -> bf16 convert; z picks pair; n4 = float4 count
// ---------------------------------------------------------------------------
__global__ __launch_bounds__(256) void conv_multi(
    const float* __restrict__ s0, ushort_t* __restrict__ d0,
    const float* __restrict__ s1, ushort_t* __restrict__ d1,
    const float* __restrict__ s2, ushort_t* __restrict__ d2,
    const float* __restrict__ s3, ushort_t* __restrict__ d3, int n4)
{
    int z = blockIdx.z;
    const float* s = z == 0 ? s0 : z == 1 ? s1 : z == 2 ? s2 : s3;
    ushort_t* d    = z == 0 ? d0 : z == 1 ? d1 : z == 2 ? d2 : d3;
    int i = blockIdx.x * 256 + threadIdx.x;
    int stride = gridDim.x * 256;
    for (; i < n4; i += stride) {
        float4 v = ((const float4*)s)[i];
        uint2 pr;
        pr.x = cvtpk(v.x, v.y);
        pr.y = cvtpk(v.z, v.w);
        ((uint2*)d)[i] = pr;
    }
}

// ---------------------------------------------------------------------------
// mask tile flags at 64x64 granularity
// ---------------------------------------------------------------------------
__global__ __launch_bounds__(256) void mask_flags(const float* __restrict__ mask,
                                                  int* __restrict__ flags)
{
    int qt = blockIdx.x, kt = blockIdx.y;
    int t = threadIdx.x;
    bool nz = false;
#pragma unroll
    for (int i = 0; i < 4; i++) {
        int idx = t + i * 256;               // 1024 float4: 64 rows x 16
        int row = idx >> 4, c4 = (idx & 15) * 4;
        float4 v = *(const float4*)(mask + (size_t)(qt * 64 + row) * SEQ + kt * 64 + c4);
        nz |= (v.x != 0.f) | (v.y != 0.f) | (v.z != 0.f) | (v.w != 0.f);
    }
    if (__any((int)nz) && (t & 63) == 0) atomicOr(&flags[qt * 32 + kt], 1);
}

// ---------------------------------------------------------------------------
// GEMM staging, XOR-SWIZZLED LDS (r18-verified: conflicts 14.16M -> 0):
//   gload16 paths: pre-swizzled global source column, linear LDS dest.
//   fp32 A path (V only): loads -> cvtpk -> swizzled ds_write (r18 form;
//   r19's T14 split was defeated by compiler load-sinking, VGPR stayed 68).
// ---------------------------------------------------------------------------
__device__ __forceinline__ void stageB_bf16(const ushort_t* __restrict__ B,
                                            int n0, int t, int w, int k0,
                                            ushort_t* sB)
{
#pragma unroll
    for (int r = 0; r < 2; r++) {
        int chunk = r * 256 + t;
        int row = chunk >> 3, cc = (chunk & 7) ^ (row & 7);
        gload16(B + (size_t)(n0 + row) * D_MODEL + k0 + cc * 8,
                &sB[(r * 256 + w * 64) * 8]);
    }
}

__device__ __forceinline__ void stageA_bf16(const ushort_t* __restrict__ A,
                                            int m0, int t, int w, int k0,
                                            ushort_t* sA)
{
#pragma unroll
    for (int r = 0; r < 4; r++) {
        int chunk = r * 256 + t;                   // 1024 chunks of 8 bf16
        int row = chunk >> 3, cc = (chunk & 7) ^ (row & 7);
        gload16(A + (size_t)(m0 + row) * D_MODEL + k0 + cc * 8,
                &sA[(r * 256 + w * 64) * 8]);
    }
}

__device__ __forceinline__ void stageA_f32(const float* __restrict__ A,
                                           int m0, int t, int k0,
                                           ushort_t* sA)
{
#pragma unroll
    for (int r = 0; r < 4; r++) {
        int chunk = r * 256 + t;
        int row = chunk >> 3, c = chunk & 7;
        const float* src = A + (size_t)(m0 + row) * D_MODEL + k0 + c * 8;
        float4 v0 = *(const float4*)src;
        float4 v1 = *(const float4*)(src + 4);
        u32x4 pw;
        pw[0] = cvtpk(v0.x, v0.y); pw[1] = cvtpk(v0.z, v0.w);
        pw[2] = cvtpk(v1.x, v1.y); pw[3] = cvtpk(v1.z, v1.w);
        int by = (row * 128 + c * 16) ^ ((row & 7) << 4);   // swizzled dest
        *(u32x4*)((char*)sA + by) = pw;
    }
}

// ---------------------------------------------------------------------------
// fused QKV projection: z=0 Aq@Wq^T -> Qb (scaled); z=1 Ak@Wk^T -> Kb
// (both bf16-A, fast gload16 path -- r19 finding: fp32-A path is ~2.4x
// slower than gload16); z=2 vx@Wv^T -> VT (fp32-A in-kernel, no ws left).
// BM=128 BN=64 BK=64, 2-phase dbuf, 1536 blocks = 3/CU. Swizzled LDS.
// ---------------------------------------------------------------------------
__global__ __launch_bounds__(256) void gemm_qkv(const ushort_t* __restrict__ Aq,
                                                const ushort_t* __restrict__ Ak,
                                                const float* __restrict__ vx,
                                                const ushort_t* __restrict__ Wq,
                                                const ushort_t* __restrict__ Wk,
                                                const ushort_t* __restrict__ Wv,
                                                ushort_t* __restrict__ Qo,
                                                ushort_t* __restrict__ Ko,
                                                ushort_t* __restrict__ VT)
{
    __shared__ ushort_t sA[2][128 * 64];
    __shared__ ushort_t sB[2][64 * 64];
    const int z = blockIdx.z;
    const ushort_t* Abf = z ? Ak : Aq;
    const ushort_t* W = z == 0 ? Wq : z == 1 ? Wk : Wv;
    const int t = threadIdx.x, lane = t & 63, w = t >> 6;
    const int lr = lane & 15, lg = lane >> 4;
    const int wm = (w >> 1) * 64, wn = (w & 1) * 32;
    const int m0 = blockIdx.x * 128, n0 = blockIdx.y * 64;

    f32x4 acc[4][2];
    f32x4 zero = {0.f, 0.f, 0.f, 0.f};
#pragma unroll
    for (int i = 0; i < 4; i++)
#pragma unroll
        for (int j = 0; j < 2; j++) acc[i][j] = zero;

    stageB_bf16(W, n0, t, w, 0, &sB[0][0]);
    if (z < 2) stageA_bf16(Abf, m0, t, w, 0, &sA[0][0]);
    else       stageA_f32(vx, m0, t, 0, &sA[0][0]);
    __syncthreads();

    for (int it = 0; it < D_MODEL / 64; ++it) {
        const int cur = it & 1;
        const char* cA = (const char*)&sA[cur][0];
        const char* cB = (const char*)&sB[cur][0];
        const bool more = (it + 1 < D_MODEL / 64);

        // ---- ds_read all fragments of current buffer FIRST (swizzled) ----
        us8 af[4][2], bfr[2][2];
#pragma unroll
        for (int i = 0; i < 4; i++)
#pragma unroll
            for (int ks = 0; ks < 2; ks++) {
                int row = wm + i * 16 + lr;
                af[i][ks] = *(const us8*)(cA + ((row * 128 + (ks * 32 + 8 * lg) * 2)
                                                ^ ((row & 7) << 4)));
            }
#pragma unroll
        for (int j = 0; j < 2; j++)
#pragma unroll
            for (int ks = 0; ks < 2; ks++) {
                int row = wn + j * 16 + lr;
                bfr[j][ks] = *(const us8*)(cB + ((row * 128 + (ks * 32 + 8 * lg) * 2)
                                                 ^ ((row & 7) << 4)));
            }

        // ---- stage next tile (after reads, per r9 alias lesson) ----
        if (more) {
            stageB_bf16(W, n0, t, w, (it + 1) * 64, &sB[cur ^ 1][0]);
            if (z < 2) stageA_bf16(Abf, m0, t, w, (it + 1) * 64, &sA[cur ^ 1][0]);
            else       stageA_f32(vx, m0, t, (it + 1) * 64, &sA[cur ^ 1][0]);
        }

        // ---- MFMA ----
#pragma unroll
        for (int i = 0; i < 4; i++)
#pragma unroll
            for (int j = 0; j < 2; j++)
#pragma unroll
                for (int ks = 0; ks < 2; ks++)
                    acc[i][j] = mfma16(af[i][ks], bfr[j][ks], acc[i][j]);

        __syncthreads();
    }

    // ---- epilogues ----
    if (z < 2) {
        ushort_t* C = z ? Ko : Qo;
        const float scale = z ? 1.0f : 0.125f * LOG2E;   // scores in log2 units
#pragma unroll
        for (int i = 0; i < 4; i++)
#pragma unroll
            for (int j = 0; j < 2; j++)
#pragma unroll
                for (int r = 0; r < 4; r++) {
                    int m = m0 + wm + i * 16 + 4 * lg + r;   // token (b*S+s)
                    int n = n0 + wn + j * 16 + lr;           // feature
                    int b = m >> 11, s = m & 2047;
                    int h = n >> 6, dh = n & 63;
                    C[(((size_t)(b * NH + h)) * SEQ + s) * DH + dh] = f2bf1(acc[i][j][r] * scale);
                }
    } else {
#pragma unroll
        for (int i = 0; i < 4; i++)
#pragma unroll
            for (int j = 0; j < 2; j++) {
                int m = m0 + wm + i * 16 + 4 * lg;           // s base; r adds 0..3
                int n = n0 + wn + j * 16 + lr;
                int b = m >> 11, s = m & 2047;
                int h = n >> 6, dh = n & 63;
                uint2 pr;
                pr.x = cvtpk(acc[i][j][0], acc[i][j][1]);
                pr.y = cvtpk(acc[i][j][2], acc[i][j][3]);
                *(uint2*)&VT[(((size_t)(b * NH + h)) * DH + dh) * SEQ + s] = pr;
            }
    }
}

// output projection: A bf16 [4096][1024] @ W0^T -> fp32 [4096][1024]
// (2-phase dbuf, swizzled LDS, gload16 both operands)
__global__ __launch_bounds__(256) void gemm_o(const ushort_t* __restrict__ A,
                                              const ushort_t* __restrict__ W,
                                              float* __restrict__ C)
{
    __shared__ ushort_t sA[2][128 * 64];
    __shared__ ushort_t sB[2][64 * 64];
    const int t = threadIdx.x, lane = t & 63, w = t >> 6;
    const int lr = lane & 15, lg = lane >> 4;
    const int wm = (w >> 1) * 64, wn = (w & 1) * 32;
    const int m0 = blockIdx.x * 128, n0 = blockIdx.y * 64;

    f32x4 acc[4][2];
    f32x4 zero = {0.f, 0.f, 0.f, 0.f};
#pragma unroll
    for (int i = 0; i < 4; i++)
#pragma unroll
        for (int j = 0; j < 2; j++) acc[i][j] = zero;

    stageA_bf16(A, m0, t, w, 0, &sA[0][0]);
    stageB_bf16(W, n0, t, w, 0, &sB[0][0]);
    __syncthreads();

    for (int it = 0; it < D_MODEL / 64; ++it) {
        const int cur = it & 1;
        const char* cA = (const char*)&sA[cur][0];
        const char* cB = (const char*)&sB[cur][0];

        us8 af[4][2], bfr[2][2];
#pragma unroll
        for (int i = 0; i < 4; i++)
#pragma unroll
            for (int ks = 0; ks < 2; ks++) {
                int row = wm + i * 16 + lr;
                af[i][ks] = *(const us8*)(cA + ((row * 128 + (ks * 32 + 8 * lg) * 2)
                                                ^ ((row & 7) << 4)));
            }
#pragma unroll
        for (int j = 0; j < 2; j++)
#pragma unroll
            for (int ks = 0; ks < 2; ks++) {
                int row = wn + j * 16 + lr;
                bfr[j][ks] = *(const us8*)(cB + ((row * 128 + (ks * 32 + 8 * lg) * 2)
                                                 ^ ((row & 7) << 4)));
            }

        if (it + 1 < D_MODEL / 64) {
            stageA_bf16(A, m0, t, w, (it + 1) * 64, &sA[cur ^ 1][0]);
            stageB_bf16(W, n0, t, w, (it + 1) * 64, &sB[cur ^ 1][0]);
        }

#pragma unroll
        for (int i = 0; i < 4; i++)
#pragma unroll
            for (int j = 0; j < 2; j++)
#pragma unroll
                for (int ks = 0; ks < 2; ks++)
                    acc[i][j] = mfma16(af[i][ks], bfr[j][ks], acc[i][j]);

        __syncthreads();
    }

#pragma unroll
    for (int i = 0; i < 4; i++)
#pragma unroll
        for (int j = 0; j < 2; j++)
#pragma unroll
            for (int r = 0; r < 4; r++) {
                int m = m0 + wm + i * 16 + 4 * lg + r;
                int n = n0 + wn + j * 16 + lr;
                C[(size_t)m * D_MODEL + n] = acc[i][j][r];
            }
}

// ---------------------------------------------------------------------------
// Flash attention (round-15 exact): swapped-operand 32x32x16, KVBLK=64 dbuf,
// 32 KB LDS, launch_bounds(256,2), max-free softmax, permlane P-assembly,
// l on VALU, XCD swizzle, hoisted stage ptrs.
// C/D layout (HW-verified): col=lane&31, row=(r&3)+8*(r>>2)+4*(lane>>5).
// ---------------------------------------------------------------------------
__global__ __launch_bounds__(256, 2) void attn_fwd(const ushort_t* __restrict__ Q,
                                                   const ushort_t* __restrict__ K,
                                                   const ushort_t* __restrict__ VT,
                                                   const float* __restrict__ mask,
                                                   const int* __restrict__ flags,
                                                   ushort_t* __restrict__ O)
{
    __shared__ ushort_t sK[2][64 * 64];     // 64 kv rows x 64 dh  (8 KB each)
    __shared__ ushort_t sVT[2][64 * 64];    // 64 dh rows x 64 kv

    const int t = threadIdx.x, lane = t & 63, w = t >> 6;
    const int l31 = lane & 31, lh = lane >> 5;
    const int id = blockIdx.x;
    const int bh = (id & 7) * 4 + ((id >> 3) >> 4);   // XCD-contiguous heads
    const int qt = (id >> 3) & 15;
    const int b = bh >> 4, h = bh & 15;
    const int q = qt * 128 + w * 32 + l31;   // lane's q row

    // mask-tile flags for this 128-row q block (2 flag rows ORed); bit = 64-col tile
    unsigned long long blt = __ballot(flags[(qt * 2 + lh) * 32 + l31] != 0);
    const unsigned int fl = (unsigned int)(blt | (blt >> 32));

    // Q fragments: B-operand rows = q, k(d)-slots 16*ks + 8*lh + e
    us8 qfr[4];
#pragma unroll
    for (int ks = 0; ks < 4; ks++)
        qfr[ks] = *(const us8*)(Q + ((size_t)bh * SEQ + q) * DH + ks * 16 + 8 * lh);

    f32x16 acc_o[2];
#pragma unroll
    for (int d = 0; d < 2; d++)
#pragma unroll
        for (int r = 0; r < 16; r++) acc_o[d][r] = 0.f;
    float acc_l = 0.f;

    const ushort_t* Kb = K + (size_t)bh * SEQ * DH;
    const ushort_t* Vb = VT + (size_t)bh * DH * SEQ;

    // hoisted per-thread staging source pointers (advance by const per tile)
    const ushort_t* kp[2];
    const ushort_t* vp[2];
#pragma unroll
    for (int r = 0; r < 2; r++) {
        int j = r * 256 + t;                 // 512 chunks of 16B per tensor
        int row = j >> 3, cc = (j & 7) ^ (row & 7);
        kp[r] = Kb + (size_t)row * DH + cc * 8;
        vp[r] = Vb + (size_t)row * SEQ + cc * 8;
    }

#define STAGE(kvt_, buf_)                                                     \
    {                                                                         \
        _Pragma("unroll")                                                     \
        for (int r = 0; r < 2; r++)                                           \
            gload16(kp[r] + (size_t)(kvt_) * (64 * DH),                       \
                    &sK[buf_][(r * 256 + w * 64) * 8]);                       \
        _Pragma("unroll")                                                     \
        for (int r = 0; r < 2; r++)                                           \
            gload16(vp[r] + (size_t)(kvt_) * 64,                              \
                    &sVT[buf_][(r * 256 + w * 64) * 8]);                      \
    }

    STAGE(0, 0);
    __syncthreads();

    for (int kvt = 0; kvt < SEQ / 64; ++kvt) {
        const int cur = kvt & 1;
        const char* cK = (const char*)sK[cur];
        const char* cV = (const char*)sVT[cur];

        // ---- S = K Q^T: sacc[kb][r] = S[kcol=kb*32+crow(r,lh)][q] ----
        f32x16 sacc[2];
#pragma unroll
        for (int kb = 0; kb < 2; kb++)
#pragma unroll
            for (int r = 0; r < 16; r++) sacc[kb][r] = 0.f;
        __builtin_amdgcn_s_setprio(1);
#pragma unroll
        for (int ks = 0; ks < 4; ks++)
#pragma unroll
            for (int kb = 0; kb < 2; kb++) {
                int row = kb * 32 + l31;
                int by = (row * 128 + (ks * 16 + 8 * lh) * 2) ^ ((row & 7) << 4);
                us8 kf = *(const us8*)(cK + by);
                sacc[kb] = mfma32(kf, qfr[ks], sacc[kb]);
            }
        __builtin_amdgcn_s_setprio(0);

        // ---- V-frag reads (last ds_reads of this tile) ----
        us8 vf[4][2];
#pragma unroll
        for (int ks = 0; ks < 4; ks++)
#pragma unroll
            for (int dblk = 0; dblk < 2; dblk++) {
                int row = dblk * 32 + l31;
                int by = (row * 128 + (ks * 16 + 8 * lh) * 2) ^ ((row & 7) << 4);
                vf[ks][dblk] = *(const us8*)(cV + by);
            }

        // ---- stage next tile; loads hide under softmax + PV ----
        if (kvt + 1 < SEQ / 64) STAGE(kvt + 1, cur ^ 1);

        // ---- additive mask (log2; skipped when 64-col tile all-zero) ----
        if ((fl >> kvt) & 1u) {
#pragma unroll
            for (int kb = 0; kb < 2; kb++)
#pragma unroll
                for (int r = 0; r < 16; r++) {
                    int kcol = kb * 32 + (r & 3) + 8 * (r >> 2) + 4 * lh;
                    sacc[kb][r] += mask[(size_t)q * SEQ + kvt * 64 + kcol] * LOG2E;
                }
        }

        // ---- P = exp2(S) in place (max-free); l partial sum ----
        float rs = 0.f;
#pragma unroll
        for (int kb = 0; kb < 2; kb++)
#pragma unroll
            for (int r = 0; r < 16; r++) {
                float p = exp2_fast(sacc[kb][r]);
                sacc[kb][r] = p;
                rs += p;
            }
        rs += __shfl_xor(rs, 32);
        acc_l += rs;

        // ---- PV: P B-frags via cvt_pk + permlane32_swap (verified r12) ----
        __builtin_amdgcn_s_setprio(1);
#pragma unroll
        for (int ks = 0; ks < 4; ks++) {
            const int kb = ks >> 1, u = ks & 1;
            unsigned int W0 = cvtpk(sacc[kb][8 * u + 0], sacc[kb][8 * u + 1]);
            unsigned int W1 = cvtpk(sacc[kb][8 * u + 2], sacc[kb][8 * u + 3]);
            unsigned int W2 = cvtpk(sacc[kb][8 * u + 4], sacc[kb][8 * u + 5]);
            unsigned int W3 = cvtpk(sacc[kb][8 * u + 6], sacc[kb][8 * u + 7]);
            asm("v_permlane32_swap_b32 %0, %1" : "+v"(W0), "+v"(W2));
            asm("v_permlane32_swap_b32 %0, %1" : "+v"(W1), "+v"(W3));
            u32x4 pw;
            pw[0] = W0; pw[1] = W1; pw[2] = W2; pw[3] = W3;
            us8 pf = __builtin_bit_cast(us8, pw);
#pragma unroll
            for (int dblk = 0; dblk < 2; dblk++)
                acc_o[dblk] = mfma32(vf[ks][dblk], pf, acc_o[dblk]);
        }
        __builtin_amdgcn_s_setprio(0);

        __syncthreads();   // drains stage(kvt+1); protects buf reuse
    }

    // ---- normalize + write [B*S][D] bf16 (d = dblk*32 + 8g + 4lh + 0..3) ----
    float inv = 1.f / acc_l;
    ushort_t* Orow = O + ((size_t)(b * SEQ) + q) * D_MODEL + h * DH;
#pragma unroll
    for (int dblk = 0; dblk < 2; dblk++)
#pragma unroll
        for (int g = 0; g < 4; g++) {
            unsigned int lo = cvtpk(acc_o[dblk][4 * g + 0] * inv,
                                    acc_o[dblk][4 * g + 1] * inv);
            unsigned int hi = cvtpk(acc_o[dblk][4 * g + 2] * inv,
                                    acc_o[dblk][4 * g + 3] * inv);
            uint2 pr; pr.x = lo; pr.y = hi;
            *(uint2*)(Orow + dblk * 32 + 8 * g + 4 * lh) = pr;
        }
#undef STAGE
}

// ---------------------------------------------------------------------------
extern "C" void kernel_launch(void* const* d_in, const int* in_sizes, int n_in,
                              void* d_out, int out_size, void* d_ws, size_t ws_size,
                              hipStream_t stream)
{
    const float* qx   = (const float*)d_in[0];
    const float* kx   = (const float*)d_in[1];
    const float* vx   = (const float*)d_in[2];
    const float* mask = (const float*)d_in[3];
    const float* wq   = (const float*)d_in[4];
    const float* wk   = (const float*)d_in[5];
    const float* wv   = (const float*)d_in[6];
    const float* w0   = (const float*)d_in[7];
    float* out = (float*)d_out;

    char* ws = (char*)d_ws;
    const size_t MB = 1024 * 1024;
    ushort_t* Aq = (ushort_t*)(ws);                 // qx bf16, 8 MB
    ushort_t* Ak = (ushort_t*)(ws + 8 * MB);        // kx bf16, 8 MB; dead after
    ushort_t* AO = (ushort_t*)(ws + 8 * MB);        //   gemm_qkv -> AO reuses it
    ushort_t* Wq = (ushort_t*)(ws + 16 * MB);       // 2 MB each
    ushort_t* Wk = (ushort_t*)(ws + 18 * MB);
    ushort_t* Wv = (ushort_t*)(ws + 20 * MB);
    ushort_t* W0 = (ushort_t*)(ws + 22 * MB);
    ushort_t* VT = (ushort_t*)(ws + 24 * MB);       // [B,H,Dh,S] bf16, 8 MB
    int* flags   = (int*)(ws + 32 * MB);            // [32][32]
    // Q and K (bf16, [B,H,S,Dh]) live in d_out until attn consumes them
    ushort_t* Qb = (ushort_t*)d_out;
    ushort_t* Kb = (ushort_t*)d_out + 4 * MB;       // +8 MB bytes

    hipMemsetAsync(flags, 0, 32 * 32 * sizeof(int), stream);
    mask_flags<<<dim3(32, 32), 256, 0, stream>>>(mask, flags);

    // weights fp32 -> bf16 (one fused launch)
    conv_multi<<<dim3(256, 1, 4), 256, 0, stream>>>(wq, Wq, wk, Wk, wv, Wv, w0, W0, 262144);
    // qx, kx fp32 -> bf16 (TLP-hidden memory pass; fp32-A GEMM path is 2.4x
    // slower than gload16 bf16 path per r19 counters)
    conv_multi<<<dim3(1024, 1, 2), 256, 0, stream>>>(qx, Aq, kx, Ak, qx, Aq, qx, Aq, 1048576);

    // fused QKV projections: z=0,1 bf16-A (fast), z=2 fp32-A (in-kernel conv)
    gemm_qkv<<<dim3(32, 16, 3), 256, 0, stream>>>(Aq, Ak, vx, Wq, Wk, Wv, Qb, Kb, VT);

    attn_fwd<<<512, 256, 0, stream>>>(Qb, Kb, VT, mask, flags, AO);

    gemm_o<<<dim3(32, 16), 256, 0, stream>>>(AO, W0, out);
}

// Round 21
// 125.385 us; speedup vs baseline: 1.0588x; 1.0148x over previous
//
#include <hip/hip_runtime.h>
#include <hip/hip_bf16.h>
#include <stdint.h>

#define D_MODEL 1024
#define NH 16
#define DH 64
#define SEQ 2048
#define MROWS 4096   // B*S
#define LOG2E 1.44269504088896340736f

typedef unsigned short ushort_t;
typedef __attribute__((ext_vector_type(4))) float f32x4;
typedef __attribute__((ext_vector_type(16))) float f32x16;
typedef __attribute__((ext_vector_type(4))) unsigned short us4;
typedef __attribute__((ext_vector_type(8))) unsigned short us8;
typedef __attribute__((ext_vector_type(4))) unsigned int u32x4;
typedef __attribute__((ext_vector_type(8))) __bf16 bf16x8;

__device__ __forceinline__ f32x4 mfma16(us8 a, us8 b, f32x4 c) {
    return __builtin_amdgcn_mfma_f32_16x16x32_bf16(
        __builtin_bit_cast(bf16x8, a), __builtin_bit_cast(bf16x8, b), c, 0, 0, 0);
}
__device__ __forceinline__ f32x16 mfma32(us8 a, us8 b, f32x16 c) {
    return __builtin_amdgcn_mfma_f32_32x32x16_bf16(
        __builtin_bit_cast(bf16x8, a), __builtin_bit_cast(bf16x8, b), c, 0, 0, 0);
}

// packed f32x2 -> bf16x2, RNE (verified == manual RNE in rounds 7-20)
__device__ __forceinline__ unsigned int cvtpk(float lo, float hi) {
    unsigned int r;
    asm("v_cvt_pk_bf16_f32 %0, %1, %2" : "=v"(r) : "v"(lo), "v"(hi));
    return r;
}
// single f32 -> bf16 (1 VALU op)
__device__ __forceinline__ ushort_t f2bf1(float f) {
    return (ushort_t)(cvtpk(f, f) & 0xffffu);
}

__device__ __forceinline__ float exp2_fast(float x) {
#if __has_builtin(__builtin_amdgcn_exp2f)
    return __builtin_amdgcn_exp2f(x);
#else
    float r; asm("v_exp_f32 %0, %1" : "=v"(r) : "v"(x)); return r;
#endif
}

// async global->LDS, 16B per lane; LDS base wave-uniform, lane i at base+i*16
__device__ __forceinline__ void gload16(const void* g, void* l) {
    __builtin_amdgcn_global_load_lds(
        (const __attribute__((address_space(1))) void*)g,
        (__attribute__((address_space(3))) void*)l, 16, 0, 0);
}

// ---------------------------------------------------------------------------
// fused fp32 -> bf16 convert; z picks pair; n4 = float4 count
// ---------------------------------------------------------------------------
__global__ __launch_bounds__(256) void conv_multi(
    const float* __restrict__ s0, ushort_t* __restrict__ d0,
    const float* __restrict__ s1, ushort_t* __restrict__ d1,
    const float* __restrict__ s2, ushort_t* __restrict__ d2,
    const float* __restrict__ s3, ushort_t* __restrict__ d3, int n4)
{
    int z = blockIdx.z;
    const float* s = z == 0 ? s0 : z == 1 ? s1 : z == 2 ? s2 : s3;
    ushort_t* d    = z == 0 ? d0 : z == 1 ? d1 : z == 2 ? d2 : d3;
    int i = blockIdx.x * 256 + threadIdx.x;
    int stride = gridDim.x * 256;
    for (; i < n4; i += stride) {
        float4 v = ((const float4*)s)[i];
        uint2 pr;
        pr.x = cvtpk(v.x, v.y);
        pr.y = cvtpk(v.z, v.w);
        ((uint2*)d)[i] = pr;
    }
}

// ---------------------------------------------------------------------------
// mask tile flags at 64x64 granularity
// ---------------------------------------------------------------------------
__global__ __launch_bounds__(256) void mask_flags(const float* __restrict__ mask,
                                                  int* __restrict__ flags)
{
    int qt = blockIdx.x, kt = blockIdx.y;
    int t = threadIdx.x;
    bool nz = false;
#pragma unroll
    for (int i = 0; i < 4; i++) {
        int idx = t + i * 256;               // 1024 float4: 64 rows x 16
        int row = idx >> 4, c4 = (idx & 15) * 4;
        float4 v = *(const float4*)(mask + (size_t)(qt * 64 + row) * SEQ + kt * 64 + c4);
        nz |= (v.x != 0.f) | (v.y != 0.f) | (v.z != 0.f) | (v.w != 0.f);
    }
    if (__any((int)nz) && (t & 63) == 0) atomicOr(&flags[qt * 32 + kt], 1);
}

// ---------------------------------------------------------------------------
// GEMM staging, XOR-SWIZZLED LDS (r18-verified: conflicts 14.16M -> 0):
//   gload16 paths: pre-swizzled global source column, linear LDS dest.
//   fp32 A path (V fallback only): loads -> cvtpk -> swizzled ds_write.
// ---------------------------------------------------------------------------
__device__ __forceinline__ void stageB_bf16(const ushort_t* __restrict__ B,
                                            int n0, int t, int w, int k0,
                                            ushort_t* sB)
{
#pragma unroll
    for (int r = 0; r < 2; r++) {
        int chunk = r * 256 + t;
        int row = chunk >> 3, cc = (chunk & 7) ^ (row & 7);
        gload16(B + (size_t)(n0 + row) * D_MODEL + k0 + cc * 8,
                &sB[(r * 256 + w * 64) * 8]);
    }
}

__device__ __forceinline__ void stageA_bf16(const ushort_t* __restrict__ A,
                                            int m0, int t, int w, int k0,
                                            ushort_t* sA)
{
#pragma unroll
    for (int r = 0; r < 4; r++) {
        int chunk = r * 256 + t;                   // 1024 chunks of 8 bf16
        int row = chunk >> 3, cc = (chunk & 7) ^ (row & 7);
        gload16(A + (size_t)(m0 + row) * D_MODEL + k0 + cc * 8,
                &sA[(r * 256 + w * 64) * 8]);
    }
}

__device__ __forceinline__ void stageA_f32(const float* __restrict__ A,
                                           int m0, int t, int k0,
                                           ushort_t* sA)
{
#pragma unroll
    for (int r = 0; r < 4; r++) {
        int chunk = r * 256 + t;
        int row = chunk >> 3, c = chunk & 7;
        const float* src = A + (size_t)(m0 + row) * D_MODEL + k0 + c * 8;
        float4 v0 = *(const float4*)src;
        float4 v1 = *(const float4*)(src + 4);
        u32x4 pw;
        pw[0] = cvtpk(v0.x, v0.y); pw[1] = cvtpk(v0.z, v0.w);
        pw[2] = cvtpk(v1.x, v1.y); pw[3] = cvtpk(v1.z, v1.w);
        int by = (row * 128 + c * 16) ^ ((row & 7) << 4);   // swizzled dest
        *(u32x4*)((char*)sA + by) = pw;
    }
}

// ---------------------------------------------------------------------------
// fused QKV projection: z=0 Aq@Wq^T -> Qb (scaled); z=1 Ak@Wk^T -> Kb;
// z=2 V -> VT ([B,H,Dh,S]): uses bf16 Av (fast gload16) when Av != null,
// else in-kernel fp32 conversion from vx (r20 fallback; ws too small).
// BM=128 BN=64 BK=64, 2-phase dbuf, 1536 blocks = 3/CU. Swizzled LDS.
// ---------------------------------------------------------------------------
__global__ __launch_bounds__(256) void gemm_qkv(const ushort_t* __restrict__ Aq,
                                                const ushort_t* __restrict__ Ak,
                                                const ushort_t* __restrict__ Av,
                                                const float* __restrict__ vx,
                                                const ushort_t* __restrict__ Wq,
                                                const ushort_t* __restrict__ Wk,
                                                const ushort_t* __restrict__ Wv,
                                                ushort_t* __restrict__ Qo,
                                                ushort_t* __restrict__ Ko,
                                                ushort_t* __restrict__ VT)
{
    __shared__ ushort_t sA[2][128 * 64];
    __shared__ ushort_t sB[2][64 * 64];
    const int z = blockIdx.z;
    const ushort_t* Abf = z == 0 ? Aq : z == 1 ? Ak : Av;
    const ushort_t* W = z == 0 ? Wq : z == 1 ? Wk : Wv;
    const bool f32path = (z == 2) && (Av == nullptr);
    const int t = threadIdx.x, lane = t & 63, w = t >> 6;
    const int lr = lane & 15, lg = lane >> 4;
    const int wm = (w >> 1) * 64, wn = (w & 1) * 32;
    const int m0 = blockIdx.x * 128, n0 = blockIdx.y * 64;

    f32x4 acc[4][2];
    f32x4 zero = {0.f, 0.f, 0.f, 0.f};
#pragma unroll
    for (int i = 0; i < 4; i++)
#pragma unroll
        for (int j = 0; j < 2; j++) acc[i][j] = zero;

    stageB_bf16(W, n0, t, w, 0, &sB[0][0]);
    if (!f32path) stageA_bf16(Abf, m0, t, w, 0, &sA[0][0]);
    else          stageA_f32(vx, m0, t, 0, &sA[0][0]);
    __syncthreads();

    for (int it = 0; it < D_MODEL / 64; ++it) {
        const int cur = it & 1;
        const char* cA = (const char*)&sA[cur][0];
        const char* cB = (const char*)&sB[cur][0];
        const bool more = (it + 1 < D_MODEL / 64);

        // ---- ds_read all fragments of current buffer FIRST (swizzled) ----
        us8 af[4][2], bfr[2][2];
#pragma unroll
        for (int i = 0; i < 4; i++)
#pragma unroll
            for (int ks = 0; ks < 2; ks++) {
                int row = wm + i * 16 + lr;
                af[i][ks] = *(const us8*)(cA + ((row * 128 + (ks * 32 + 8 * lg) * 2)
                                                ^ ((row & 7) << 4)));
            }
#pragma unroll
        for (int j = 0; j < 2; j++)
#pragma unroll
            for (int ks = 0; ks < 2; ks++) {
                int row = wn + j * 16 + lr;
                bfr[j][ks] = *(const us8*)(cB + ((row * 128 + (ks * 32 + 8 * lg) * 2)
                                                 ^ ((row & 7) << 4)));
            }

        // ---- stage next tile (after reads, per r9 alias lesson) ----
        if (more) {
            stageB_bf16(W, n0, t, w, (it + 1) * 64, &sB[cur ^ 1][0]);
            if (!f32path) stageA_bf16(Abf, m0, t, w, (it + 1) * 64, &sA[cur ^ 1][0]);
            else          stageA_f32(vx, m0, t, (it + 1) * 64, &sA[cur ^ 1][0]);
        }

        // ---- MFMA ----
#pragma unroll
        for (int i = 0; i < 4; i++)
#pragma unroll
            for (int j = 0; j < 2; j++)
#pragma unroll
                for (int ks = 0; ks < 2; ks++)
                    acc[i][j] = mfma16(af[i][ks], bfr[j][ks], acc[i][j]);

        __syncthreads();
    }

    // ---- epilogues ----
    if (z < 2) {
        ushort_t* C = z ? Ko : Qo;
        const float scale = z ? 1.0f : 0.125f * LOG2E;   // scores in log2 units
#pragma unroll
        for (int i = 0; i < 4; i++)
#pragma unroll
            for (int j = 0; j < 2; j++)
#pragma unroll
                for (int r = 0; r < 4; r++) {
                    int m = m0 + wm + i * 16 + 4 * lg + r;   // token (b*S+s)
                    int n = n0 + wn + j * 16 + lr;           // feature
                    int b = m >> 11, s = m & 2047;
                    int h = n >> 6, dh = n & 63;
                    C[(((size_t)(b * NH + h)) * SEQ + s) * DH + dh] = f2bf1(acc[i][j][r] * scale);
                }
    } else {
#pragma unroll
        for (int i = 0; i < 4; i++)
#pragma unroll
            for (int j = 0; j < 2; j++) {
                int m = m0 + wm + i * 16 + 4 * lg;           // s base; r adds 0..3
                int n = n0 + wn + j * 16 + lr;
                int b = m >> 11, s = m & 2047;
                int h = n >> 6, dh = n & 63;
                uint2 pr;
                pr.x = cvtpk(acc[i][j][0], acc[i][j][1]);
                pr.y = cvtpk(acc[i][j][2], acc[i][j][3]);
                *(uint2*)&VT[(((size_t)(b * NH + h)) * DH + dh) * SEQ + s] = pr;
            }
    }
}

// output projection: A bf16 [4096][1024] @ W0^T -> fp32 [4096][1024]
// (2-phase dbuf, swizzled LDS, gload16 both operands)
__global__ __launch_bounds__(256) void gemm_o(const ushort_t* __restrict__ A,
                                              const ushort_t* __restrict__ W,
                                              float* __restrict__ C)
{
    __shared__ ushort_t sA[2][128 * 64];
    __shared__ ushort_t sB[2][64 * 64];
    const int t = threadIdx.x, lane = t & 63, w = t >> 6;
    const int lr = lane & 15, lg = lane >> 4;
    const int wm = (w >> 1) * 64, wn = (w & 1) * 32;
    const int m0 = blockIdx.x * 128, n0 = blockIdx.y * 64;

    f32x4 acc[4][2];
    f32x4 zero = {0.f, 0.f, 0.f, 0.f};
#pragma unroll
    for (int i = 0; i < 4; i++)
#pragma unroll
        for (int j = 0; j < 2; j++) acc[i][j] = zero;

    stageA_bf16(A, m0, t, w, 0, &sA[0][0]);
    stageB_bf16(W, n0, t, w, 0, &sB[0][0]);
    __syncthreads();

    for (int it = 0; it < D_MODEL / 64; ++it) {
        const int cur = it & 1;
        const char* cA = (const char*)&sA[cur][0];
        const char* cB = (const char*)&sB[cur][0];

        us8 af[4][2], bfr[2][2];
#pragma unroll
        for (int i = 0; i < 4; i++)
#pragma unroll
            for (int ks = 0; ks < 2; ks++) {
                int row = wm + i * 16 + lr;
                af[i][ks] = *(const us8*)(cA + ((row * 128 + (ks * 32 + 8 * lg) * 2)
                                                ^ ((row & 7) << 4)));
            }
#pragma unroll
        for (int j = 0; j < 2; j++)
#pragma unroll
            for (int ks = 0; ks < 2; ks++) {
                int row = wn + j * 16 + lr;
                bfr[j][ks] = *(const us8*)(cB + ((row * 128 + (ks * 32 + 8 * lg) * 2)
                                                 ^ ((row & 7) << 4)));
            }

        if (it + 1 < D_MODEL / 64) {
            stageA_bf16(A, m0, t, w, (it + 1) * 64, &sA[cur ^ 1][0]);
            stageB_bf16(W, n0, t, w, (it + 1) * 64, &sB[cur ^ 1][0]);
        }

#pragma unroll
        for (int i = 0; i < 4; i++)
#pragma unroll
            for (int j = 0; j < 2; j++)
#pragma unroll
                for (int ks = 0; ks < 2; ks++)
                    acc[i][j] = mfma16(af[i][ks], bfr[j][ks], acc[i][j]);

        __syncthreads();
    }

#pragma unroll
    for (int i = 0; i < 4; i++)
#pragma unroll
        for (int j = 0; j < 2; j++)
#pragma unroll
            for (int r = 0; r < 4; r++) {
                int m = m0 + wm + i * 16 + 4 * lg + r;
                int n = n0 + wn + j * 16 + lr;
                C[(size_t)m * D_MODEL + n] = acc[i][j][r];
            }
}

// ---------------------------------------------------------------------------
// Flash attention (round-15 exact): swapped-operand 32x32x16, KVBLK=64 dbuf,
// 32 KB LDS, launch_bounds(256,2), max-free softmax, permlane P-assembly,
// l on VALU, XCD swizzle, hoisted stage ptrs.
// C/D layout (HW-verified): col=lane&31, row=(r&3)+8*(r>>2)+4*(lane>>5).
// ---------------------------------------------------------------------------
__global__ __launch_bounds__(256, 2) void attn_fwd(const ushort_t* __restrict__ Q,
                                                   const ushort_t* __restrict__ K,
                                                   const ushort_t* __restrict__ VT,
                                                   const float* __restrict__ mask,
                                                   const int* __restrict__ flags,
                                                   ushort_t* __restrict__ O)
{
    __shared__ ushort_t sK[2][64 * 64];     // 64 kv rows x 64 dh  (8 KB each)
    __shared__ ushort_t sVT[2][64 * 64];    // 64 dh rows x 64 kv

    const int t = threadIdx.x, lane = t & 63, w = t >> 6;
    const int l31 = lane & 31, lh = lane >> 5;
    const int id = blockIdx.x;
    const int bh = (id & 7) * 4 + ((id >> 3) >> 4);   // XCD-contiguous heads
    const int qt = (id >> 3) & 15;
    const int b = bh >> 4, h = bh & 15;
    const int q = qt * 128 + w * 32 + l31;   // lane's q row

    // mask-tile flags for this 128-row q block (2 flag rows ORed); bit = 64-col tile
    unsigned long long blt = __ballot(flags[(qt * 2 + lh) * 32 + l31] != 0);
    const unsigned int fl = (unsigned int)(blt | (blt >> 32));

    // Q fragments: B-operand rows = q, k(d)-slots 16*ks + 8*lh + e
    us8 qfr[4];
#pragma unroll
    for (int ks = 0; ks < 4; ks++)
        qfr[ks] = *(const us8*)(Q + ((size_t)bh * SEQ + q) * DH + ks * 16 + 8 * lh);

    f32x16 acc_o[2];
#pragma unroll
    for (int d = 0; d < 2; d++)
#pragma unroll
        for (int r = 0; r < 16; r++) acc_o[d][r] = 0.f;
    float acc_l = 0.f;

    const ushort_t* Kb = K + (size_t)bh * SEQ * DH;
    const ushort_t* Vb = VT + (size_t)bh * DH * SEQ;

    // hoisted per-thread staging source pointers (advance by const per tile)
    const ushort_t* kp[2];
    const ushort_t* vp[2];
#pragma unroll
    for (int r = 0; r < 2; r++) {
        int j = r * 256 + t;                 // 512 chunks of 16B per tensor
        int row = j >> 3, cc = (j & 7) ^ (row & 7);
        kp[r] = Kb + (size_t)row * DH + cc * 8;
        vp[r] = Vb + (size_t)row * SEQ + cc * 8;
    }

#define STAGE(kvt_, buf_)                                                     \
    {                                                                         \
        _Pragma("unroll")                                                     \
        for (int r = 0; r < 2; r++)                                           \
            gload16(kp[r] + (size_t)(kvt_) * (64 * DH),                       \
                    &sK[buf_][(r * 256 + w * 64) * 8]);                       \
        _Pragma("unroll")                                                     \
        for (int r = 0; r < 2; r++)                                           \
            gload16(vp[r] + (size_t)(kvt_) * 64,                              \
                    &sVT[buf_][(r * 256 + w * 64) * 8]);                      \
    }

    STAGE(0, 0);
    __syncthreads();

    for (int kvt = 0; kvt < SEQ / 64; ++kvt) {
        const int cur = kvt & 1;
        const char* cK = (const char*)sK[cur];
        const char* cV = (const char*)sVT[cur];

        // ---- S = K Q^T: sacc[kb][r] = S[kcol=kb*32+crow(r,lh)][q] ----
        f32x16 sacc[2];
#pragma unroll
        for (int kb = 0; kb < 2; kb++)
#pragma unroll
            for (int r = 0; r < 16; r++) sacc[kb][r] = 0.f;
        __builtin_amdgcn_s_setprio(1);
#pragma unroll
        for (int ks = 0; ks < 4; ks++)
#pragma unroll
            for (int kb = 0; kb < 2; kb++) {
                int row = kb * 32 + l31;
                int by = (row * 128 + (ks * 16 + 8 * lh) * 2) ^ ((row & 7) << 4);
                us8 kf = *(const us8*)(cK + by);
                sacc[kb] = mfma32(kf, qfr[ks], sacc[kb]);
            }
        __builtin_amdgcn_s_setprio(0);

        // ---- V-frag reads (last ds_reads of this tile) ----
        us8 vf[4][2];
#pragma unroll
        for (int ks = 0; ks < 4; ks++)
#pragma unroll
            for (int dblk = 0; dblk < 2; dblk++) {
                int row = dblk * 32 + l31;
                int by = (row * 128 + (ks * 16 + 8 * lh) * 2) ^ ((row & 7) << 4);
                vf[ks][dblk] = *(const us8*)(cV + by);
            }

        // ---- stage next tile; loads hide under softmax + PV ----
        if (kvt + 1 < SEQ / 64) STAGE(kvt + 1, cur ^ 1);

        // ---- additive mask (log2; skipped when 64-col tile all-zero) ----
        if ((fl >> kvt) & 1u) {
#pragma unroll
            for (int kb = 0; kb < 2; kb++)
#pragma unroll
                for (int r = 0; r < 16; r++) {
                    int kcol = kb * 32 + (r & 3) + 8 * (r >> 2) + 4 * lh;
                    sacc[kb][r] += mask[(size_t)q * SEQ + kvt * 64 + kcol] * LOG2E;
                }
        }

        // ---- P = exp2(S) in place (max-free); l partial sum ----
        float rs = 0.f;
#pragma unroll
        for (int kb = 0; kb < 2; kb++)
#pragma unroll
            for (int r = 0; r < 16; r++) {
                float p = exp2_fast(sacc[kb][r]);
                sacc[kb][r] = p;
                rs += p;
            }
        rs += __shfl_xor(rs, 32);
        acc_l += rs;

        // ---- PV: P B-frags via cvt_pk + permlane32_swap (verified r12) ----
        __builtin_amdgcn_s_setprio(1);
#pragma unroll
        for (int ks = 0; ks < 4; ks++) {
            const int kb = ks >> 1, u = ks & 1;
            unsigned int W0 = cvtpk(sacc[kb][8 * u + 0], sacc[kb][8 * u + 1]);
            unsigned int W1 = cvtpk(sacc[kb][8 * u + 2], sacc[kb][8 * u + 3]);
            unsigned int W2 = cvtpk(sacc[kb][8 * u + 4], sacc[kb][8 * u + 5]);
            unsigned int W3 = cvtpk(sacc[kb][8 * u + 6], sacc[kb][8 * u + 7]);
            asm("v_permlane32_swap_b32 %0, %1" : "+v"(W0), "+v"(W2));
            asm("v_permlane32_swap_b32 %0, %1" : "+v"(W1), "+v"(W3));
            u32x4 pw;
            pw[0] = W0; pw[1] = W1; pw[2] = W2; pw[3] = W3;
            us8 pf = __builtin_bit_cast(us8, pw);
#pragma unroll
            for (int dblk = 0; dblk < 2; dblk++)
                acc_o[dblk] = mfma32(vf[ks][dblk], pf, acc_o[dblk]);
        }
        __builtin_amdgcn_s_setprio(0);

        __syncthreads();   // drains stage(kvt+1); protects buf reuse
    }

    // ---- normalize + write [B*S][D] bf16 (d = dblk*32 + 8g + 4lh + 0..3) ----
    float inv = 1.f / acc_l;
    ushort_t* Orow = O + ((size_t)(b * SEQ) + q) * D_MODEL + h * DH;
#pragma unroll
    for (int dblk = 0; dblk < 2; dblk++)
#pragma unroll
        for (int g = 0; g < 4; g++) {
            unsigned int lo = cvtpk(acc_o[dblk][4 * g + 0] * inv,
                                    acc_o[dblk][4 * g + 1] * inv);
            unsigned int hi = cvtpk(acc_o[dblk][4 * g + 2] * inv,
                                    acc_o[dblk][4 * g + 3] * inv);
            uint2 pr; pr.x = lo; pr.y = hi;
            *(uint2*)(Orow + dblk * 32 + 8 * g + 4 * lh) = pr;
        }
#undef STAGE
}

// ---------------------------------------------------------------------------
extern "C" void kernel_launch(void* const* d_in, const int* in_sizes, int n_in,
                              void* d_out, int out_size, void* d_ws, size_t ws_size,
                              hipStream_t stream)
{
    const float* qx   = (const float*)d_in[0];
    const float* kx   = (const float*)d_in[1];
    const float* vx   = (const float*)d_in[2];
    const float* mask = (const float*)d_in[3];
    const float* wq   = (const float*)d_in[4];
    const float* wk   = (const float*)d_in[5];
    const float* wv   = (const float*)d_in[6];
    const float* w0   = (const float*)d_in[7];
    float* out = (float*)d_out;

    char* ws = (char*)d_ws;
    const size_t MB = 1024 * 1024;
    ushort_t* Aq = (ushort_t*)(ws);                 // qx bf16, 8 MB
    ushort_t* Ak = (ushort_t*)(ws + 8 * MB);        // kx bf16, 8 MB; dead after
    ushort_t* AO = (ushort_t*)(ws + 8 * MB);        //   gemm_qkv -> AO reuses it
    ushort_t* Wq = (ushort_t*)(ws + 16 * MB);       // 2 MB each
    ushort_t* Wk = (ushort_t*)(ws + 18 * MB);
    ushort_t* Wv = (ushort_t*)(ws + 20 * MB);
    ushort_t* W0 = (ushort_t*)(ws + 22 * MB);
    ushort_t* VT = (ushort_t*)(ws + 24 * MB);       // [B,H,Dh,S] bf16, 8 MB

    // ws-size probe: if workspace allows, vx also pre-converts to bf16 (Av)
    // and gemm_qkv z=2 takes the fast gload16 path (fp32-A path is ~2.4x
    // slower per r19/r20 counters). Fallback = exact r20 configuration.
    const bool bigws = (ws_size >= 41 * MB);
    ushort_t* Av = bigws ? (ushort_t*)(ws + 32 * MB) : nullptr;   // 8 MB
    int* flags   = (int*)(ws + (bigws ? 40 * MB : 32 * MB));      // [32][32]

    // Q and K (bf16, [B,H,S,Dh]) live in d_out until attn consumes them
    ushort_t* Qb = (ushort_t*)d_out;
    ushort_t* Kb = (ushort_t*)d_out + 4 * MB;       // +8 MB bytes

    hipMemsetAsync(flags, 0, 32 * 32 * sizeof(int), stream);
    mask_flags<<<dim3(32, 32), 256, 0, stream>>>(mask, flags);

    // weights fp32 -> bf16 (one fused launch)
    conv_multi<<<dim3(256, 1, 4), 256, 0, stream>>>(wq, Wq, wk, Wk, wv, Wv, w0, W0, 262144);
    // inputs fp32 -> bf16 (qx, kx always; vx too when workspace allows)
    conv_multi<<<dim3(1024, 1, bigws ? 3 : 2), 256, 0, stream>>>(
        qx, Aq, kx, Ak, vx, bigws ? Av : Aq, qx, Aq, 1048576);

    // fused QKV projections: all-bf16 when bigws, else z=2 fp32 in-kernel
    gemm_qkv<<<dim3(32, 16, 3), 256, 0, stream>>>(Aq, Ak, Av, vx,
                                                  Wq, Wk, Wv, Qb, Kb, VT);

    attn_fwd<<<512, 256, 0, stream>>>(Qb, Kb, VT, mask, flags, AO);

    gemm_o<<<dim3(32, 16), 256, 0, stream>>>(AO, W0, out);
}